// Round 17
// baseline (334.530 us; speedup 1.0000x reference)
//
#include <hip/hip_runtime.h>
#include <hip/hip_bf16.h>

#define BB 8
#define NP 4096
#define STRIDE 4
#define KNN 32
#define NS (NP/STRIDE)      // 1024
#define NQ (BB*NS)          // 8192
#define DIN 67
#define H1N 128
#define H2N 256
#define WCAP 512            // survivor cap per wave segment
#define GRID 2048           // persistent-ish: 4 queries per block

typedef __attribute__((ext_vector_type(8)))  short bf16x8;
typedef __attribute__((ext_vector_type(16))) float f32x16;
typedef __attribute__((ext_vector_type(8)))  short short8;

// ---------- helpers ----------
__device__ __forceinline__ unsigned int f2u(float f) {
    unsigned int b = __float_as_uint(f);
    return (b & 0x80000000u) ? ~b : (b | 0x80000000u);
}
__device__ __forceinline__ short f2bf(float f) {   // RNE float->bf16 bits
    unsigned u = __float_as_uint(f);
    unsigned r = u + 0x7FFFu + ((u >> 16) & 1u);
    return (short)(r >> 16);
}
__device__ __forceinline__ int pack2(float a, float b) {
    return (int)((unsigned short)f2bf(a) | ((unsigned)(unsigned short)f2bf(b) << 16));
}

// ---------- fused: KNN + gather + MFMA MLP; grid-stride, 4 queries/block sequential ----------
__global__ __launch_bounds__(256) void fused_kernel(const float* __restrict__ pos,
                                                    const float* __restrict__ x,
                                                    const short* __restrict__ W1T,
                                                    const short* __restrict__ W2T,
                                                    const float* __restrict__ b1,
                                                    const float* __restrict__ b2,
                                                    float* __restrict__ out) {
    __shared__ __align__(16) unsigned long long surv[4 * WCAP];   // 16 KB; reused by MLP
    __shared__ unsigned int pvt[4];
    __shared__ int cnts[4];
    __shared__ int col_l[KNN];

    const int t    = threadIdx.x;
    const int w    = t >> 6;
    const int lane = t & 63;

    for (int q = blockIdx.x; q < NQ; q += GRID) {

    const int b    = q >> 10;
    const int s    = q & (NS - 1);
    const int qi   = b * NP + s * STRIDE;

    // tail outputs
    if (t < 5) {
        float* pos_out   = out + (size_t)NQ * H2N;
        float* batch_out = pos_out + (size_t)NQ * 3;
        float* idx_out   = batch_out + NQ;
        if (t < 3)       pos_out[q*3+t] = pos[qi*3+t];
        else if (t == 3) batch_out[q] = (float)b;
        else             idx_out[q]   = (float)qi;
    }

    const float qx = pos[qi*3+0], qy = pos[qi*3+1], qz = pos[qi*3+2];
    const float q2 = __fadd_rn(__fadd_rn(__fmul_rn(qx,qx), __fmul_rn(qy,qy)), __fmul_rn(qz,qz));

    // ---- distance phase (exact reference rounding) ----
    const float* pb = pos + (size_t)b * NP * 3;
    unsigned int myk[16];
    #pragma unroll
    for (int i = 0; i < 4; ++i) {
        const int u = t + i * 256;
        const float4* pp = (const float4*)(pb + (size_t)u * 12);
        const float4 v0 = pp[0], v1 = pp[1], v2 = pp[2];
        const float px[4] = {v0.x, v0.w, v1.z, v2.y};
        const float py[4] = {v0.y, v1.x, v1.w, v2.z};
        const float pz[4] = {v0.z, v1.y, v2.x, v2.w};
        #pragma unroll
        for (int j = 0; j < 4; ++j) {
            const float p2 = __fadd_rn(__fadd_rn(__fmul_rn(px[j],px[j]), __fmul_rn(py[j],py[j])), __fmul_rn(pz[j],pz[j]));
            const float dt = __fadd_rn(__fadd_rn(__fmul_rn(qx,px[j]), __fmul_rn(qy,py[j])), __fmul_rn(qz,pz[j]));
            const float d2 = __fsub_rn(__fadd_rn(q2, p2), __fmul_rn(2.0f, dt));
            myk[i*4+j] = f2u(d2);
        }
    }

    // ---- pivot: wave 0 ranks its 64 myk[0] keys via shfl ladder ----
    if (t < 64) {
        const unsigned int mk = myk[0];
        int rank = 0;
        #pragma unroll
        for (int ss = 0; ss < 64; ++ss) {
            const unsigned int ks = (unsigned int)__shfl((int)mk, ss, 64);
            rank += (int)((ks < mk) | ((ks == mk) & (ss < t)));
        }
        if (rank == 1)  pvt[0] = mk;
        if (rank == 3)  pvt[1] = mk;
        if (rank == 8)  pvt[2] = mk;
        if (rank == 31) pvt[3] = mk;   // guarantees C >= 32
    }
    __syncthreads();     // also protects surv/cnts/col_l reuse across loop iterations

    // ---- write-first compact at level 0 ----
    int cw;
    {
        const unsigned int T = pvt[0];
        int base = 0;
        #pragma unroll
        for (int i = 0; i < 16; ++i) {
            const bool p = (myk[i] <= T);
            const unsigned long long mask = __ballot(p);
            if (p) {
                const int off = base + (int)__popcll(mask & ((1ull << lane) - 1ull));
                if (off < WCAP) {
                    const int n = 4 * (t + (i >> 2) * 256) + (i & 3);
                    surv[(w << 9) + off] = ((unsigned long long)myk[i] << 32) | (unsigned int)n;
                }
            }
            base += (int)__popcll(mask);
        }
        cw = (base < WCAP) ? base : WCAP;
    }
    if (lane == 0) cnts[w] = cw;
    __syncthreads();

    int c0 = cnts[0], c1 = cnts[1], c2 = cnts[2], c3 = cnts[3];
    int C = c0 + c1 + c2 + c3;

    // ---- rare escalation (~8.5%) ----
    if (C < KNN) {
        int level;
        for (level = 1; level < 4; ++level) {
            const unsigned int T = pvt[level];
            int cnt = 0;
            #pragma unroll
            for (int i = 0; i < 16; ++i)
                cnt += (int)__popcll(__ballot(myk[i] <= T));
            if (lane == 0) cnts[w] = cnt;
            __syncthreads();
            C = cnts[0] + cnts[1] + cnts[2] + cnts[3];
            if (C >= KNN) break;
            __syncthreads();
        }
        if (level > 3) level = 3;
        __syncthreads();
        {
            const unsigned int T = pvt[level];
            int base = 0;
            #pragma unroll
            for (int i = 0; i < 16; ++i) {
                const bool p = (myk[i] <= T);
                const unsigned long long mask = __ballot(p);
                if (p) {
                    const int off = base + (int)__popcll(mask & ((1ull << lane) - 1ull));
                    if (off < WCAP) {
                        const int n = 4 * (t + (i >> 2) * 256) + (i & 3);
                        surv[(w << 9) + off] = ((unsigned long long)myk[i] << 32) | (unsigned int)n;
                    }
                }
                base += (int)__popcll(mask);
            }
            cw = (base < WCAP) ? base : WCAP;
        }
        if (lane == 0) cnts[w] = cw;
        __syncthreads();
        c0 = cnts[0]; c1 = cnts[1]; c2 = cnts[2]; c3 = cnts[3];
        C = c0 + c1 + c2 + c3;
    }

    // pad wave segments to multiple of 8 with +inf sentinels
    {
        const int cwp = (cw + 7) & ~7;
        for (int i = cw + lane; i < cwp; i += 64)
            surv[(w << 9) + i] = ~0ull;
    }
    __syncthreads();

    // ---- flat exact-rank pass -> col_l (u64 = (key, index) reference tie order) ----
    const int s1 = c0, s2 = c0 + c1, s3 = c0 + c1 + c2;
    const int cseg[4] = {c0, c1, c2, c3};
    for (int j = t; j < C; j += 256) {
        const int seg = (int)(j >= s1) + (int)(j >= s2) + (int)(j >= s3);
        const int off = j - ((seg == 0) ? 0 : (seg == 1) ? s1 : (seg == 2) ? s2 : s3);
        const unsigned long long v = surv[(seg << 9) + off];
        int rk = 0;
        #pragma unroll 1
        for (int k = 0; k < 4; ++k) {
            const int np = ((cseg[k] + 7) & ~7) >> 1;
            const ulonglong2* sp = (const ulonglong2*)(surv + (k << 9));
            #pragma unroll 4
            for (int ss = 0; ss < np; ++ss) {
                const ulonglong2 pr = sp[ss];
                rk += (int)(pr.x < v) + (int)(pr.y < v);
            }
        }
        if (rk < KNN)
            col_l[rk] = b * NP + (int)(unsigned int)(v & 0xFFFFFFFFull);
    }
    __syncthreads();

    // ================= MLP phase (reuses surv LDS) =================
    short* feat = (short*)surv;            // 32 rows x 80 = 5120 B
    short* h1s  = ((short*)surv) + 2560;   // 32 rows x 128 = 8192 B (swizzled slots)

    // gather: row = t>>3 (0..31), part = t&7 -> 8 x-floats each
    {
        const int row = t >> 3, part = t & 7;
        const int c   = col_l[row];
        const float4* xr = (const float4*)(x + (size_t)c * 64 + part * 8);
        const float4 v0 = xr[0], v1 = xr[1];
        short* fr = feat + row * 80 + part * 8;
        *(int*)(fr + 0) = pack2(v0.x, v0.y);
        *(int*)(fr + 2) = pack2(v0.z, v0.w);
        *(int*)(fr + 4) = pack2(v1.x, v1.y);
        *(int*)(fr + 6) = pack2(v1.z, v1.w);
        if (part == 0) {
            short8 o;
            o[0] = f2bf(pos[c*3+0] - qx);
            o[1] = f2bf(pos[c*3+1] - qy);
            o[2] = f2bf(pos[c*3+2] - qz);
            o[3] = 0; o[4] = 0; o[5] = 0; o[6] = 0; o[7] = 0;
            *(short8*)(feat + row * 80 + 64) = o;
            short8 z = {0,0,0,0,0,0,0,0};
            *(short8*)(feat + row * 80 + 72) = z;
        }
    }
    __syncthreads();

    const int lr2 = lane & 31;   // row/channel lane within 32x32 tile
    const int lh  = lane >> 5;   // k-half selector

    // layer 1: wave w computes N-tile nt=w (channels 32w..32w+31)
    {
        bf16x8 w1f[5];
        #pragma unroll
        for (int kt = 0; kt < 5; ++kt)
            w1f[kt] = *(const bf16x8*)(W1T + ((size_t)(w*5 + kt) * 64 + lane) * 8);

        bf16x8 a1[5];
        #pragma unroll
        for (int kt = 0; kt < 5; ++kt)
            a1[kt] = *(const bf16x8*)(feat + lr2 * 80 + 16*kt + 8*lh);

        const float bv = b1[32*w + lr2];
        f32x16 acc;
        #pragma unroll
        for (int r = 0; r < 16; ++r) acc[r] = bv;
        #pragma unroll
        for (int kt = 0; kt < 5; ++kt)
            acc = __builtin_amdgcn_mfma_f32_32x32x16_bf16(a1[kt], w1f[kt], acc, 0, 0, 0);

        #pragma unroll
        for (int r = 0; r < 16; ++r) {
            const int i = (r & 3) + 8*(r >> 2) + 4*lh;    // row (neighbor)
            const int c = 32*w + lr2;                     // channel
            const int adr = i * 128 + ((((c >> 3) ^ (i & 15)) << 3) | (c & 7));
            h1s[adr] = f2bf(fmaxf(acc[r], 0.0f));
        }
    }
    __syncthreads();

    // layer 2: wave w handles nt in {w, w+4}; maxpool over 32 rows; bias+relu after max
    {
        bf16x8 a2[8];
        #pragma unroll
        for (int kt = 0; kt < 8; ++kt) {
            const int slot = 2*kt + lh;
            a2[kt] = *(const bf16x8*)(h1s + lr2 * 128 + ((slot ^ (lr2 & 15)) << 3));
        }

        #pragma unroll
        for (int half = 0; half < 2; ++half) {
            const int nt = w + 4*half;
            bf16x8 wf[8];
            #pragma unroll
            for (int kt = 0; kt < 8; ++kt)
                wf[kt] = *(const bf16x8*)(W2T + ((size_t)(nt*8 + kt) * 64 + lane) * 8);
            f32x16 acc;
            #pragma unroll
            for (int r = 0; r < 16; ++r) acc[r] = 0.0f;
            #pragma unroll
            for (int kt = 0; kt < 8; ++kt)
                acc = __builtin_amdgcn_mfma_f32_32x32x16_bf16(a2[kt], wf[kt], acc, 0, 0, 0);

            float m = acc[0];
            #pragma unroll
            for (int r = 1; r < 16; ++r) m = fmaxf(m, acc[r]);
            m = fmaxf(m, __shfl_xor(m, 32, 64));
            m = fmaxf(m + b2[32*nt + lr2], 0.0f);
            if (lane < 32) out[(size_t)q * H2N + 32*nt + lane] = m;
        }
    }

    }   // end grid-stride query loop
}

// ---------- merged weight prep: frag-linear bf16 layouts ----------
__global__ __launch_bounds__(64) void prep_w(const float* __restrict__ W1,
                                             const float* __restrict__ W2,
                                             short* __restrict__ W1T,
                                             short* __restrict__ W2T) {
    const int l = threadIdx.x;
    if (blockIdx.x < 20) {
        const int nt = blockIdx.x / 5, t = blockIdx.x % 5;
        const int c  = 32*nt + (l & 31);
        short8 v;
        #pragma unroll
        for (int b = 0; b < 8; ++b) {
            const int k = 16*t + 8*(l >> 5) + b;
            v[b] = (k < DIN) ? f2bf(W1[k * H1N + c]) : (short)0;
        }
        *(short8*)(W1T + ((size_t)(nt*5 + t) * 64 + l) * 8) = v;
    } else {
        const int bb = blockIdx.x - 20;
        const int nt = bb >> 3, t = bb & 7;
        const int c  = 32*nt + (l & 31);
        short8 v;
        #pragma unroll
        for (int b = 0; b < 8; ++b) {
            const int k = 16*t + 8*(l >> 5) + b;
            v[b] = f2bf(W2[k * H2N + c]);
        }
        *(short8*)(W2T + ((size_t)(nt*8 + t) * 64 + l) * 8) = v;
    }
}

extern "C" void kernel_launch(void* const* d_in, const int* in_sizes, int n_in,
                              void* d_out, int out_size, void* d_ws, size_t ws_size,
                              hipStream_t stream) {
    const float* x   = (const float*)d_in[0];
    const float* pos = (const float*)d_in[1];
    const float* W1  = (const float*)d_in[3];
    const float* b1  = (const float*)d_in[4];
    const float* W2  = (const float*)d_in[5];
    const float* b2  = (const float*)d_in[6];
    float* out = (float*)d_out;

    char* ws   = (char*)d_ws;
    short* W1T = (short*)ws;                 // 20480 B
    short* W2T = (short*)(ws + 20480);       // 65536 B

    prep_w<<<84, 64, 0, stream>>>(W1, W2, W1T, W2T);
    fused_kernel<<<GRID, 256, 0, stream>>>(pos, x, W1T, W2T, b1, b2, out);
}

// Round 18
// 288.607 us; speedup vs baseline: 1.1591x; 1.1591x over previous
//
#include <hip/hip_runtime.h>
#include <hip/hip_bf16.h>

#define BB 8
#define NP 4096
#define STRIDE 4
#define KNN 32
#define NS (NP/STRIDE)      // 1024
#define NQ (BB*NS)          // 8192
#define DIN 67
#define H1N 128
#define H2N 256
#define WCAP 512            // survivor cap per wave segment
#define GRID 2048           // 4 queries per block, sequential

typedef __attribute__((ext_vector_type(8)))  short bf16x8;
typedef __attribute__((ext_vector_type(16))) float f32x16;
typedef __attribute__((ext_vector_type(8)))  short short8;

// ---------- helpers ----------
__device__ __forceinline__ unsigned int f2u(float f) {
    unsigned int b = __float_as_uint(f);
    return (b & 0x80000000u) ? ~b : (b | 0x80000000u);
}
__device__ __forceinline__ short f2bf(float f) {   // RNE float->bf16 bits
    unsigned u = __float_as_uint(f);
    unsigned r = u + 0x7FFFu + ((u >> 16) & 1u);
    return (short)(r >> 16);
}
__device__ __forceinline__ int pack2(float a, float b) {
    return (int)((unsigned short)f2bf(a) | ((unsigned)(unsigned short)f2bf(b) << 16));
}

// ---------- fused: KNN + gather + MFMA MLP; grid-stride, VGPR-capped ----------
__global__ __launch_bounds__(256, 4) void fused_kernel(const float* __restrict__ pos,
                                                       const float* __restrict__ x,
                                                       const short* __restrict__ W1T,
                                                       const short* __restrict__ W2T,
                                                       const float* __restrict__ b1,
                                                       const float* __restrict__ b2,
                                                       float* __restrict__ out) {
    __shared__ __align__(16) unsigned long long surv[4 * WCAP];   // 16 KB; reused by MLP
    __shared__ unsigned int pvt[4];
    __shared__ int cnts[4];
    __shared__ int col_l[KNN];

    const int t    = threadIdx.x;
    const int w    = t >> 6;
    const int lane = t & 63;

    #pragma unroll 1
    for (int q = blockIdx.x; q < NQ; q += GRID) {

    const int b    = q >> 10;
    const int s    = q & (NS - 1);
    const int qi   = b * NP + s * STRIDE;

    // tail outputs
    if (t < 5) {
        float* pos_out   = out + (size_t)NQ * H2N;
        float* batch_out = pos_out + (size_t)NQ * 3;
        float* idx_out   = batch_out + NQ;
        if (t < 3)       pos_out[q*3+t] = pos[qi*3+t];
        else if (t == 3) batch_out[q] = (float)b;
        else             idx_out[q]   = (float)qi;
    }

    const float qx = pos[qi*3+0], qy = pos[qi*3+1], qz = pos[qi*3+2];
    const float q2 = __fadd_rn(__fadd_rn(__fmul_rn(qx,qx), __fmul_rn(qy,qy)), __fmul_rn(qz,qz));

    // ---- distance phase (exact reference rounding) ----
    const float* pb = pos + (size_t)b * NP * 3;
    unsigned int myk[16];
    #pragma unroll
    for (int i = 0; i < 4; ++i) {
        const int u = t + i * 256;
        const float4* pp = (const float4*)(pb + (size_t)u * 12);
        const float4 v0 = pp[0], v1 = pp[1], v2 = pp[2];
        const float px[4] = {v0.x, v0.w, v1.z, v2.y};
        const float py[4] = {v0.y, v1.x, v1.w, v2.z};
        const float pz[4] = {v0.z, v1.y, v2.x, v2.w};
        #pragma unroll
        for (int j = 0; j < 4; ++j) {
            const float p2 = __fadd_rn(__fadd_rn(__fmul_rn(px[j],px[j]), __fmul_rn(py[j],py[j])), __fmul_rn(pz[j],pz[j]));
            const float dt = __fadd_rn(__fadd_rn(__fmul_rn(qx,px[j]), __fmul_rn(qy,py[j])), __fmul_rn(qz,pz[j]));
            const float d2 = __fsub_rn(__fadd_rn(q2, p2), __fmul_rn(2.0f, dt));
            myk[i*4+j] = f2u(d2);
        }
    }

    // ---- pivot: wave 0 ranks its 64 myk[0] keys via shfl ladder ----
    if (t < 64) {
        const unsigned int mk = myk[0];
        int rank = 0;
        #pragma unroll
        for (int ss = 0; ss < 64; ++ss) {
            const unsigned int ks = (unsigned int)__shfl((int)mk, ss, 64);
            rank += (int)((ks < mk) | ((ks == mk) & (ss < t)));
        }
        if (rank == 1)  pvt[0] = mk;
        if (rank == 3)  pvt[1] = mk;
        if (rank == 8)  pvt[2] = mk;
        if (rank == 31) pvt[3] = mk;   // guarantees C >= 32
    }
    __syncthreads();     // also protects surv/cnts/col_l reuse across loop iterations

    // ---- write-first compact at level 0 ----
    int cw;
    {
        const unsigned int T = pvt[0];
        int base = 0;
        #pragma unroll
        for (int i = 0; i < 16; ++i) {
            const bool p = (myk[i] <= T);
            const unsigned long long mask = __ballot(p);
            if (p) {
                const int off = base + (int)__popcll(mask & ((1ull << lane) - 1ull));
                if (off < WCAP) {
                    const int n = 4 * (t + (i >> 2) * 256) + (i & 3);
                    surv[(w << 9) + off] = ((unsigned long long)myk[i] << 32) | (unsigned int)n;
                }
            }
            base += (int)__popcll(mask);
        }
        cw = (base < WCAP) ? base : WCAP;
    }
    if (lane == 0) cnts[w] = cw;
    __syncthreads();

    int c0 = cnts[0], c1 = cnts[1], c2 = cnts[2], c3 = cnts[3];
    int C = c0 + c1 + c2 + c3;

    // ---- rare escalation (~8.5%) ----
    if (C < KNN) {
        int level;
        for (level = 1; level < 4; ++level) {
            const unsigned int T = pvt[level];
            int cnt = 0;
            #pragma unroll
            for (int i = 0; i < 16; ++i)
                cnt += (int)__popcll(__ballot(myk[i] <= T));
            if (lane == 0) cnts[w] = cnt;
            __syncthreads();
            C = cnts[0] + cnts[1] + cnts[2] + cnts[3];
            if (C >= KNN) break;
            __syncthreads();
        }
        if (level > 3) level = 3;
        __syncthreads();
        {
            const unsigned int T = pvt[level];
            int base = 0;
            #pragma unroll
            for (int i = 0; i < 16; ++i) {
                const bool p = (myk[i] <= T);
                const unsigned long long mask = __ballot(p);
                if (p) {
                    const int off = base + (int)__popcll(mask & ((1ull << lane) - 1ull));
                    if (off < WCAP) {
                        const int n = 4 * (t + (i >> 2) * 256) + (i & 3);
                        surv[(w << 9) + off] = ((unsigned long long)myk[i] << 32) | (unsigned int)n;
                    }
                }
                base += (int)__popcll(mask);
            }
            cw = (base < WCAP) ? base : WCAP;
        }
        if (lane == 0) cnts[w] = cw;
        __syncthreads();
        c0 = cnts[0]; c1 = cnts[1]; c2 = cnts[2]; c3 = cnts[3];
        C = c0 + c1 + c2 + c3;
    }

    // pad wave segments to multiple of 8 with +inf sentinels
    {
        const int cwp = (cw + 7) & ~7;
        for (int i = cw + lane; i < cwp; i += 64)
            surv[(w << 9) + i] = ~0ull;
    }
    __syncthreads();

    // ---- flat exact-rank pass -> col_l (u64 = (key, index) reference tie order) ----
    const int s1 = c0, s2 = c0 + c1, s3 = c0 + c1 + c2;
    const int cseg[4] = {c0, c1, c2, c3};
    for (int j = t; j < C; j += 256) {
        const int seg = (int)(j >= s1) + (int)(j >= s2) + (int)(j >= s3);
        const int off = j - ((seg == 0) ? 0 : (seg == 1) ? s1 : (seg == 2) ? s2 : s3);
        const unsigned long long v = surv[(seg << 9) + off];
        int rk = 0;
        #pragma unroll 1
        for (int k = 0; k < 4; ++k) {
            const int np = ((cseg[k] + 7) & ~7) >> 1;
            const ulonglong2* sp = (const ulonglong2*)(surv + (k << 9));
            #pragma unroll 4
            for (int ss = 0; ss < np; ++ss) {
                const ulonglong2 pr = sp[ss];
                rk += (int)(pr.x < v) + (int)(pr.y < v);
            }
        }
        if (rk < KNN)
            col_l[rk] = b * NP + (int)(unsigned int)(v & 0xFFFFFFFFull);
    }
    __syncthreads();

    // ================= MLP phase (reuses surv LDS) =================
    short* feat = (short*)surv;            // 32 rows x 80 = 5120 B
    short* h1s  = ((short*)surv) + 2560;   // 32 rows x 128 = 8192 B (swizzled slots)

    // gather: row = t>>3 (0..31), part = t&7 -> 8 x-floats each
    {
        const int row = t >> 3, part = t & 7;
        const int c   = col_l[row];
        const float4* xr = (const float4*)(x + (size_t)c * 64 + part * 8);
        const float4 v0 = xr[0], v1 = xr[1];
        short* fr = feat + row * 80 + part * 8;
        *(int*)(fr + 0) = pack2(v0.x, v0.y);
        *(int*)(fr + 2) = pack2(v0.z, v0.w);
        *(int*)(fr + 4) = pack2(v1.x, v1.y);
        *(int*)(fr + 6) = pack2(v1.z, v1.w);
        if (part == 0) {
            short8 o;
            o[0] = f2bf(pos[c*3+0] - qx);
            o[1] = f2bf(pos[c*3+1] - qy);
            o[2] = f2bf(pos[c*3+2] - qz);
            o[3] = 0; o[4] = 0; o[5] = 0; o[6] = 0; o[7] = 0;
            *(short8*)(feat + row * 80 + 64) = o;
            short8 z = {0,0,0,0,0,0,0,0};
            *(short8*)(feat + row * 80 + 72) = z;
        }
    }
    __syncthreads();

    const int lr2 = lane & 31;   // row/channel lane within 32x32 tile
    const int lh  = lane >> 5;   // k-half selector

    // layer 1: wave w computes N-tile nt=w (channels 32w..32w+31)
    {
        bf16x8 w1f[5];
        #pragma unroll
        for (int kt = 0; kt < 5; ++kt)
            w1f[kt] = *(const bf16x8*)(W1T + ((size_t)(w*5 + kt) * 64 + lane) * 8);

        bf16x8 a1[5];
        #pragma unroll
        for (int kt = 0; kt < 5; ++kt)
            a1[kt] = *(const bf16x8*)(feat + lr2 * 80 + 16*kt + 8*lh);

        const float bv = b1[32*w + lr2];
        f32x16 acc;
        #pragma unroll
        for (int r = 0; r < 16; ++r) acc[r] = bv;
        #pragma unroll
        for (int kt = 0; kt < 5; ++kt)
            acc = __builtin_amdgcn_mfma_f32_32x32x16_bf16(a1[kt], w1f[kt], acc, 0, 0, 0);

        #pragma unroll
        for (int r = 0; r < 16; ++r) {
            const int i = (r & 3) + 8*(r >> 2) + 4*lh;    // row (neighbor)
            const int c = 32*w + lr2;                     // channel
            const int adr = i * 128 + ((((c >> 3) ^ (i & 15)) << 3) | (c & 7));
            h1s[adr] = f2bf(fmaxf(acc[r], 0.0f));
        }
    }
    __syncthreads();

    // layer 2: wave w handles nt in {w, w+4}; maxpool over 32 rows; bias+relu after max
    {
        bf16x8 a2[8];
        #pragma unroll
        for (int kt = 0; kt < 8; ++kt) {
            const int slot = 2*kt + lh;
            a2[kt] = *(const bf16x8*)(h1s + lr2 * 128 + ((slot ^ (lr2 & 15)) << 3));
        }

        #pragma unroll
        for (int half = 0; half < 2; ++half) {
            const int nt = w + 4*half;
            bf16x8 wf[8];
            #pragma unroll
            for (int kt = 0; kt < 8; ++kt)
                wf[kt] = *(const bf16x8*)(W2T + ((size_t)(nt*8 + kt) * 64 + lane) * 8);
            f32x16 acc;
            #pragma unroll
            for (int r = 0; r < 16; ++r) acc[r] = 0.0f;
            #pragma unroll
            for (int kt = 0; kt < 8; ++kt)
                acc = __builtin_amdgcn_mfma_f32_32x32x16_bf16(a2[kt], wf[kt], acc, 0, 0, 0);

            float m = acc[0];
            #pragma unroll
            for (int r = 1; r < 16; ++r) m = fmaxf(m, acc[r]);
            m = fmaxf(m, __shfl_xor(m, 32, 64));
            m = fmaxf(m + b2[32*nt + lr2], 0.0f);
            if (lane < 32) out[(size_t)q * H2N + 32*nt + lane] = m;
        }
    }

    __syncthreads();   // protect LDS reuse before next iteration's writes

    }   // end grid-stride query loop
}

// ---------- merged weight prep: frag-linear bf16 layouts ----------
__global__ __launch_bounds__(64) void prep_w(const float* __restrict__ W1,
                                             const float* __restrict__ W2,
                                             short* __restrict__ W1T,
                                             short* __restrict__ W2T) {
    const int l = threadIdx.x;
    if (blockIdx.x < 20) {
        const int nt = blockIdx.x / 5, t = blockIdx.x % 5;
        const int c  = 32*nt + (l & 31);
        short8 v;
        #pragma unroll
        for (int b = 0; b < 8; ++b) {
            const int k = 16*t + 8*(l >> 5) + b;
            v[b] = (k < DIN) ? f2bf(W1[k * H1N + c]) : (short)0;
        }
        *(short8*)(W1T + ((size_t)(nt*5 + t) * 64 + l) * 8) = v;
    } else {
        const int bb = blockIdx.x - 20;
        const int nt = bb >> 3, t = bb & 7;
        const int c  = 32*nt + (l & 31);
        short8 v;
        #pragma unroll
        for (int b = 0; b < 8; ++b) {
            const int k = 16*t + 8*(l >> 5) + b;
            v[b] = f2bf(W2[k * H2N + c]);
        }
        *(short8*)(W2T + ((size_t)(nt*8 + t) * 64 + l) * 8) = v;
    }
}

extern "C" void kernel_launch(void* const* d_in, const int* in_sizes, int n_in,
                              void* d_out, int out_size, void* d_ws, size_t ws_size,
                              hipStream_t stream) {
    const float* x   = (const float*)d_in[0];
    const float* pos = (const float*)d_in[1];
    const float* W1  = (const float*)d_in[3];
    const float* b1  = (const float*)d_in[4];
    const float* W2  = (const float*)d_in[5];
    const float* b2  = (const float*)d_in[6];
    float* out = (float*)d_out;

    char* ws   = (char*)d_ws;
    short* W1T = (short*)ws;                 // 20480 B
    short* W2T = (short*)(ws + 20480);       // 65536 B

    prep_w<<<84, 64, 0, stream>>>(W1, W2, W1T, W2T);
    fused_kernel<<<GRID, 256, 0, stream>>>(pos, x, W1T, W2T, b1, b2, out);
}

// Round 19
// 128.877 us; speedup vs baseline: 2.5957x; 2.2394x over previous
//
#include <hip/hip_runtime.h>
#include <hip/hip_bf16.h>

#define BB 8
#define NP 4096
#define STRIDE 4
#define KNN 32
#define NS (NP/STRIDE)      // 1024
#define NQ (BB*NS)          // 8192
#define DIN 67
#define H1N 128
#define H2N 256
#define WCAP 512            // survivor cap per wave segment

typedef __attribute__((ext_vector_type(8)))  short bf16x8;
typedef __attribute__((ext_vector_type(16))) float f32x16;
typedef __attribute__((ext_vector_type(8)))  short short8;

// ---------- helpers ----------
__device__ __forceinline__ unsigned int f2u(float f) {
    unsigned int b = __float_as_uint(f);
    return (b & 0x80000000u) ? ~b : (b | 0x80000000u);
}
__device__ __forceinline__ short f2bf(float f) {   // RNE float->bf16 bits
    unsigned u = __float_as_uint(f);
    unsigned r = u + 0x7FFFu + ((u >> 16) & 1u);
    return (short)(r >> 16);
}
__device__ __forceinline__ int pack2(float a, float b) {
    return (int)((unsigned short)f2bf(a) | ((unsigned)(unsigned short)f2bf(b) << 16));
}

// ---------- fused: KNN + gather + MFMA MLP, 1 block = 1 query (r13 champion) ----------
__global__ __launch_bounds__(256) void fused_kernel(const float* __restrict__ pos,
                                                    const float* __restrict__ x,
                                                    const short* __restrict__ W1T,
                                                    const short* __restrict__ W2T,
                                                    const float* __restrict__ b1,
                                                    const float* __restrict__ b2,
                                                    float* __restrict__ out) {
    __shared__ __align__(16) unsigned long long surv[4 * WCAP];   // 16 KB; reused by MLP
    __shared__ unsigned int pvt[4];
    __shared__ int cnts[4];
    __shared__ int col_l[KNN];

    const int q    = blockIdx.x;
    const int b    = q >> 10;
    const int s    = q & (NS - 1);
    const int qi   = b * NP + s * STRIDE;
    const int t    = threadIdx.x;
    const int w    = t >> 6;
    const int lane = t & 63;

    // tail outputs
    if (t < 5) {
        float* pos_out   = out + (size_t)NQ * H2N;
        float* batch_out = pos_out + (size_t)NQ * 3;
        float* idx_out   = batch_out + NQ;
        if (t < 3)       pos_out[q*3+t] = pos[qi*3+t];
        else if (t == 3) batch_out[q] = (float)b;
        else             idx_out[q]   = (float)qi;
    }

    const float qx = pos[qi*3+0], qy = pos[qi*3+1], qz = pos[qi*3+2];
    const float q2 = __fadd_rn(__fadd_rn(__fmul_rn(qx,qx), __fmul_rn(qy,qy)), __fmul_rn(qz,qz));

    // ---- distance phase (exact reference rounding) ----
    const float* pb = pos + (size_t)b * NP * 3;
    unsigned int myk[16];
    #pragma unroll
    for (int i = 0; i < 4; ++i) {
        const int u = t + i * 256;
        const float4* pp = (const float4*)(pb + (size_t)u * 12);
        const float4 v0 = pp[0], v1 = pp[1], v2 = pp[2];
        const float px[4] = {v0.x, v0.w, v1.z, v2.y};
        const float py[4] = {v0.y, v1.x, v1.w, v2.z};
        const float pz[4] = {v0.z, v1.y, v2.x, v2.w};
        #pragma unroll
        for (int j = 0; j < 4; ++j) {
            const float p2 = __fadd_rn(__fadd_rn(__fmul_rn(px[j],px[j]), __fmul_rn(py[j],py[j])), __fmul_rn(pz[j],pz[j]));
            const float dt = __fadd_rn(__fadd_rn(__fmul_rn(qx,px[j]), __fmul_rn(qy,py[j])), __fmul_rn(qz,pz[j]));
            const float d2 = __fsub_rn(__fadd_rn(q2, p2), __fmul_rn(2.0f, dt));
            myk[i*4+j] = f2u(d2);
        }
    }

    // ---- pivot: wave 0 ranks its 64 myk[0] keys via shfl ladder ----
    if (t < 64) {
        const unsigned int mk = myk[0];
        int rank = 0;
        #pragma unroll
        for (int ss = 0; ss < 64; ++ss) {
            const unsigned int ks = (unsigned int)__shfl((int)mk, ss, 64);
            rank += (int)((ks < mk) | ((ks == mk) & (ss < t)));
        }
        if (rank == 1)  pvt[0] = mk;
        if (rank == 3)  pvt[1] = mk;
        if (rank == 8)  pvt[2] = mk;
        if (rank == 31) pvt[3] = mk;   // guarantees C >= 32
    }
    __syncthreads();

    // ---- write-first compact at level 0 ----
    int cw;
    {
        const unsigned int T = pvt[0];
        int base = 0;
        #pragma unroll
        for (int i = 0; i < 16; ++i) {
            const bool p = (myk[i] <= T);
            const unsigned long long mask = __ballot(p);
            if (p) {
                const int off = base + (int)__popcll(mask & ((1ull << lane) - 1ull));
                if (off < WCAP) {
                    const int n = 4 * (t + (i >> 2) * 256) + (i & 3);
                    surv[(w << 9) + off] = ((unsigned long long)myk[i] << 32) | (unsigned int)n;
                }
            }
            base += (int)__popcll(mask);
        }
        cw = (base < WCAP) ? base : WCAP;
    }
    if (lane == 0) cnts[w] = cw;
    __syncthreads();

    int c0 = cnts[0], c1 = cnts[1], c2 = cnts[2], c3 = cnts[3];
    int C = c0 + c1 + c2 + c3;

    // ---- rare escalation (~8.5%) ----
    if (C < KNN) {
        int level;
        for (level = 1; level < 4; ++level) {
            const unsigned int T = pvt[level];
            int cnt = 0;
            #pragma unroll
            for (int i = 0; i < 16; ++i)
                cnt += (int)__popcll(__ballot(myk[i] <= T));
            if (lane == 0) cnts[w] = cnt;
            __syncthreads();
            C = cnts[0] + cnts[1] + cnts[2] + cnts[3];
            if (C >= KNN) break;
            __syncthreads();
        }
        if (level > 3) level = 3;
        __syncthreads();
        {
            const unsigned int T = pvt[level];
            int base = 0;
            #pragma unroll
            for (int i = 0; i < 16; ++i) {
                const bool p = (myk[i] <= T);
                const unsigned long long mask = __ballot(p);
                if (p) {
                    const int off = base + (int)__popcll(mask & ((1ull << lane) - 1ull));
                    if (off < WCAP) {
                        const int n = 4 * (t + (i >> 2) * 256) + (i & 3);
                        surv[(w << 9) + off] = ((unsigned long long)myk[i] << 32) | (unsigned int)n;
                    }
                }
                base += (int)__popcll(mask);
            }
            cw = (base < WCAP) ? base : WCAP;
        }
        if (lane == 0) cnts[w] = cw;
        __syncthreads();
        c0 = cnts[0]; c1 = cnts[1]; c2 = cnts[2]; c3 = cnts[3];
        C = c0 + c1 + c2 + c3;
    }

    // pad wave segments to multiple of 8 with +inf sentinels
    {
        const int cwp = (cw + 7) & ~7;
        for (int i = cw + lane; i < cwp; i += 64)
            surv[(w << 9) + i] = ~0ull;
    }
    __syncthreads();

    // ---- flat exact-rank pass -> col_l (set of 32 nearest, reference tie order) ----
    const int s1 = c0, s2 = c0 + c1, s3 = c0 + c1 + c2;
    const int cseg[4] = {c0, c1, c2, c3};
    for (int j = t; j < C; j += 256) {
        const int seg = (int)(j >= s1) + (int)(j >= s2) + (int)(j >= s3);
        const int off = j - ((seg == 0) ? 0 : (seg == 1) ? s1 : (seg == 2) ? s2 : s3);
        const unsigned long long v = surv[(seg << 9) + off];
        int rk = 0;
        #pragma unroll 1
        for (int k = 0; k < 4; ++k) {
            const int np = ((cseg[k] + 7) & ~7) >> 1;
            const ulonglong2* sp = (const ulonglong2*)(surv + (k << 9));
            #pragma unroll 4
            for (int ss = 0; ss < np; ++ss) {
                const ulonglong2 pr = sp[ss];
                rk += (int)(pr.x < v) + (int)(pr.y < v);
            }
        }
        if (rk < KNN)
            col_l[rk] = b * NP + (int)(unsigned int)(v & 0xFFFFFFFFull);
    }
    __syncthreads();

    // ================= MLP phase (reuses surv LDS) =================
    short* feat = (short*)surv;            // 32 rows x 80 = 5120 B
    short* h1s  = ((short*)surv) + 2560;   // 32 rows x 128 = 8192 B (swizzled slots)

    // gather: row = t>>3 (0..31), part = t&7 -> 8 x-floats each
    {
        const int row = t >> 3, part = t & 7;
        const int c   = col_l[row];
        const float4* xr = (const float4*)(x + (size_t)c * 64 + part * 8);
        const float4 v0 = xr[0], v1 = xr[1];
        short* fr = feat + row * 80 + part * 8;
        *(int*)(fr + 0) = pack2(v0.x, v0.y);
        *(int*)(fr + 2) = pack2(v0.z, v0.w);
        *(int*)(fr + 4) = pack2(v1.x, v1.y);
        *(int*)(fr + 6) = pack2(v1.z, v1.w);
        if (part == 0) {
            short8 o;
            o[0] = f2bf(pos[c*3+0] - qx);
            o[1] = f2bf(pos[c*3+1] - qy);
            o[2] = f2bf(pos[c*3+2] - qz);
            o[3] = 0; o[4] = 0; o[5] = 0; o[6] = 0; o[7] = 0;
            *(short8*)(feat + row * 80 + 64) = o;
            short8 z = {0,0,0,0,0,0,0,0};
            *(short8*)(feat + row * 80 + 72) = z;
        }
    }
    __syncthreads();

    const int lr2 = lane & 31;   // row/channel lane within 32x32 tile
    const int lh  = lane >> 5;   // k-half selector

    // layer 1: wave w computes N-tile nt=w (channels 32w..32w+31)
    {
        bf16x8 w1f[5];
        #pragma unroll
        for (int kt = 0; kt < 5; ++kt)
            w1f[kt] = *(const bf16x8*)(W1T + ((size_t)(w*5 + kt) * 64 + lane) * 8);

        bf16x8 a1[5];
        #pragma unroll
        for (int kt = 0; kt < 5; ++kt)
            a1[kt] = *(const bf16x8*)(feat + lr2 * 80 + 16*kt + 8*lh);

        const float bv = b1[32*w + lr2];
        f32x16 acc;
        #pragma unroll
        for (int r = 0; r < 16; ++r) acc[r] = bv;
        #pragma unroll
        for (int kt = 0; kt < 5; ++kt)
            acc = __builtin_amdgcn_mfma_f32_32x32x16_bf16(a1[kt], w1f[kt], acc, 0, 0, 0);

        #pragma unroll
        for (int r = 0; r < 16; ++r) {
            const int i = (r & 3) + 8*(r >> 2) + 4*lh;    // row (neighbor)
            const int c = 32*w + lr2;                     // channel
            const int adr = i * 128 + ((((c >> 3) ^ (i & 15)) << 3) | (c & 7));
            h1s[adr] = f2bf(fmaxf(acc[r], 0.0f));
        }
    }
    __syncthreads();

    // layer 2: wave w handles nt in {w, w+4}; maxpool over 32 rows; bias+relu after max
    {
        bf16x8 a2[8];
        #pragma unroll
        for (int kt = 0; kt < 8; ++kt) {
            const int slot = 2*kt + lh;
            a2[kt] = *(const bf16x8*)(h1s + lr2 * 128 + ((slot ^ (lr2 & 15)) << 3));
        }

        #pragma unroll
        for (int half = 0; half < 2; ++half) {
            const int nt = w + 4*half;
            bf16x8 wf[8];
            #pragma unroll
            for (int kt = 0; kt < 8; ++kt)
                wf[kt] = *(const bf16x8*)(W2T + ((size_t)(nt*8 + kt) * 64 + lane) * 8);
            f32x16 acc;
            #pragma unroll
            for (int r = 0; r < 16; ++r) acc[r] = 0.0f;
            #pragma unroll
            for (int kt = 0; kt < 8; ++kt)
                acc = __builtin_amdgcn_mfma_f32_32x32x16_bf16(a2[kt], wf[kt], acc, 0, 0, 0);

            float m = acc[0];
            #pragma unroll
            for (int r = 1; r < 16; ++r) m = fmaxf(m, acc[r]);
            m = fmaxf(m, __shfl_xor(m, 32, 64));
            m = fmaxf(m + b2[32*nt + lr2], 0.0f);
            if (lane < 32) out[(size_t)q * H2N + 32*nt + lane] = m;
        }
    }
}

// ---------- merged weight prep: frag-linear bf16 layouts ----------
__global__ __launch_bounds__(64) void prep_w(const float* __restrict__ W1,
                                             const float* __restrict__ W2,
                                             short* __restrict__ W1T,
                                             short* __restrict__ W2T) {
    const int l = threadIdx.x;
    if (blockIdx.x < 20) {
        const int nt = blockIdx.x / 5, t = blockIdx.x % 5;
        const int c  = 32*nt + (l & 31);
        short8 v;
        #pragma unroll
        for (int b = 0; b < 8; ++b) {
            const int k = 16*t + 8*(l >> 5) + b;
            v[b] = (k < DIN) ? f2bf(W1[k * H1N + c]) : (short)0;
        }
        *(short8*)(W1T + ((size_t)(nt*5 + t) * 64 + l) * 8) = v;
    } else {
        const int bb = blockIdx.x - 20;
        const int nt = bb >> 3, t = bb & 7;
        const int c  = 32*nt + (l & 31);
        short8 v;
        #pragma unroll
        for (int b = 0; b < 8; ++b) {
            const int k = 16*t + 8*(l >> 5) + b;
            v[b] = f2bf(W2[k * H2N + c]);
        }
        *(short8*)(W2T + ((size_t)(nt*8 + t) * 64 + l) * 8) = v;
    }
}

extern "C" void kernel_launch(void* const* d_in, const int* in_sizes, int n_in,
                              void* d_out, int out_size, void* d_ws, size_t ws_size,
                              hipStream_t stream) {
    const float* x   = (const float*)d_in[0];
    const float* pos = (const float*)d_in[1];
    const float* W1  = (const float*)d_in[3];
    const float* b1  = (const float*)d_in[4];
    const float* W2  = (const float*)d_in[5];
    const float* b2  = (const float*)d_in[6];
    float* out = (float*)d_out;

    char* ws   = (char*)d_ws;
    short* W1T = (short*)ws;                 // 20480 B
    short* W2T = (short*)(ws + 20480);       // 65536 B

    prep_w<<<84, 64, 0, stream>>>(W1, W2, W1T, W2T);
    fused_kernel<<<NQ, 256, 0, stream>>>(pos, x, W1T, W2T, b1, b2, out);
}